// Round 3
// baseline (107.965 us; speedup 1.0000x reference)
//
#include <hip/hip_runtime.h>
#include <math.h>

// OuterLaplaceAggregation: complex first-order linear scan, REAL part stored.
//   s_t = lambda * s_{t-1} + x_t,  s_{-1} = memory,  out[b,t,f,c] = Re(s_t)
//   lambda_{f,c} = exp(clip(a[f],-LIMIT,-1e-8) + i*b[c])
// B=8 T=512 F=1024 C=4. Harness compares real parts only (complex64
// .astype(float32)): out_size = 16,777,216 floats, layout [b,t,f,c].
//
// 3-kernel chunked scan (T = 16 chunks x 32):
//   p1:   chunk-local end states e_j (zero init)        -> ws_e
//   comb: S_j = lam^32 * S_{j-1} + e_{j-1}, S_0 = mem   -> ws_s
//   p2:   re-scan chunk from S_j, write Re as float4 (c=0..3 per thread)

#define BB 8
#define TT 512
#define FF 1024
#define CC 4
#define NCH 16
#define LL (TT / NCH)          // 32
#define LIMIT_F 0.07664339751178941f

__device__ __forceinline__ void make_lambda(const float* __restrict__ a_vec,
                                            const float* __restrict__ b_vec,
                                            int f, float lr[CC], float li[CC])
{
    const float af = fminf(fmaxf(a_vec[f], -LIMIT_F), -1e-8f);
    const float ea = expf(af);
#pragma unroll
    for (int c = 0; c < CC; ++c) {
        float s, cz;
        sincosf(b_vec[c], &s, &cz);
        lr[c] = ea * cz;
        li[c] = ea * s;
    }
}

// ---- phase 1: chunk-local scans, zero init. thread = (b, f, j) ----
__global__ __launch_bounds__(256) void
p1_kernel(const float* __restrict__ x,
          const float* __restrict__ a_vec,
          const float* __restrict__ b_vec,
          float* __restrict__ ws_e,
          long long x_lim, long long ws_lim)
{
    const int g = blockIdx.x * 256 + threadIdx.x;   // [0, 131072)
    const int f = g & (FF - 1);
    const int b = (g >> 10) & (BB - 1);
    const int j = g >> 13;                          // 0..15

    float lr[CC], li[CC];
    make_lambda(a_vec, b_vec, f, lr, li);

    const long long xbase = ((long long)b * TT + j * LL) * FF + f;
    const bool xok = (xbase + (long long)(LL - 1) * FF) < x_lim;

    float sr[CC] = {0.f, 0.f, 0.f, 0.f}, si[CC] = {0.f, 0.f, 0.f, 0.f};
#pragma unroll 4
    for (int t = 0; t < LL; ++t) {
        const float xv = xok ? x[xbase + (long long)t * FF] : 0.f;
#pragma unroll
        for (int c = 0; c < CC; ++c) {
            const float nr = fmaf(lr[c], sr[c], fmaf(-li[c], si[c], xv));
            const float ni = fmaf(li[c], sr[c], lr[c] * si[c]);
            sr[c] = nr; si[c] = ni;
        }
    }
    // ws_e layout: [j][b][f][c][re,im] -> 8 consecutive floats per thread
    const long long w = (((long long)j * BB + b) * FF + f) * 8;
    if (w + 7 < ws_lim) {
        float4* w4 = (float4*)(ws_e + w);
        w4[0] = make_float4(sr[0], si[0], sr[1], si[1]);
        w4[1] = make_float4(sr[2], si[2], sr[3], si[3]);
    }
}

// ---- combine: serial scan over chunks. thread = (b, f, c) ----
__global__ __launch_bounds__(256) void
comb_kernel(const float* __restrict__ mem_r,
            const float* __restrict__ mem_i,
            const float* __restrict__ a_vec,
            const float* __restrict__ b_vec,
            const float* __restrict__ ws_e,
            float* __restrict__ ws_s,
            long long mem_lim, long long ws_lim)
{
    const int g = blockIdx.x * 256 + threadIdx.x;   // [0, 32768)
    const int c = g & 3;
    const int f = (g >> 2) & (FF - 1);
    const int b = g >> 12;

    const float af = fminf(fmaxf(a_vec[f], -LIMIT_F), -1e-8f);
    const float eaL = expf(af * (float)LL);
    float sL, cL;
    sincosf(b_vec[c] * (float)LL, &sL, &cL);
    const float lLr = eaL * cL, lLi = eaL * sL;

    const long long m = (long long)(b * FF + f) * CC + c;
    float Sr = (m < mem_lim) ? mem_r[m] : 0.f;
    float Si = (m < mem_lim) ? mem_i[m] : 0.f;

    const long long base = ((long long)b * FF + f) * 8 + 2 * c;
    const long long slab = (long long)BB * FF * 8;   // floats per j-slab
    for (int j = 0; j < NCH; ++j) {
        const long long o = (long long)j * slab + base;
        if (o + 1 < ws_lim) { ws_s[o] = Sr; ws_s[o + 1] = Si; }
        float er = 0.f, ei = 0.f;
        if (o + 1 < ws_lim) { er = ws_e[o]; ei = ws_e[o + 1]; }
        const float nr = fmaf(lLr, Sr, fmaf(-lLi, Si, er));
        const float ni = fmaf(lLi, Sr, fmaf(lLr, Si, ei));
        Sr = nr; Si = ni;
    }
}

// ---- phase 2: re-scan from seed, write Re (and optionally planar Im) ----
__global__ __launch_bounds__(256) void
p2_kernel(const float* __restrict__ x,
          const float* __restrict__ a_vec,
          const float* __restrict__ b_vec,
          const float* __restrict__ ws_s,
          float* __restrict__ out,
          long long x_lim, long long ws_lim, long long out4_lim,
          long long imag_off4)
{
    const int g = blockIdx.x * 256 + threadIdx.x;   // [0, 131072)
    const int f = g & (FF - 1);
    const int b = (g >> 10) & (BB - 1);
    const int j = g >> 13;

    float lr[CC], li[CC];
    make_lambda(a_vec, b_vec, f, lr, li);

    float sr[CC] = {0.f, 0.f, 0.f, 0.f}, si[CC] = {0.f, 0.f, 0.f, 0.f};
    const long long sidx = (((long long)j * BB + b) * FF + f) * 8;
    if (sidx + 7 < ws_lim) {
        const float4* s4 = (const float4*)(ws_s + sidx);
        const float4 A = s4[0], Bv = s4[1];
        sr[0] = A.x;  si[0] = A.y;  sr[1] = A.z;  si[1] = A.w;
        sr[2] = Bv.x; si[2] = Bv.y; sr[3] = Bv.z; si[3] = Bv.w;
    }

    const long long xbase = ((long long)b * TT + j * LL) * FF + f;
    const bool xok = (xbase + (long long)(LL - 1) * FF) < x_lim;

    float4* out4 = (float4*)out;
    const long long obase = xbase;   // float4 index: (b*T + t)*F + f
    const bool rok = (obase + (long long)(LL - 1) * FF) < out4_lim;
    const bool iok = (imag_off4 > 0) &&
                     ((obase + imag_off4 + (long long)(LL - 1) * FF) < out4_lim);

#pragma unroll 4
    for (int t = 0; t < LL; ++t) {
        const float xv = xok ? x[xbase + (long long)t * FF] : 0.f;
#pragma unroll
        for (int c = 0; c < CC; ++c) {
            const float nr = fmaf(lr[c], sr[c], fmaf(-li[c], si[c], xv));
            const float ni = fmaf(li[c], sr[c], lr[c] * si[c]);
            sr[c] = nr; si[c] = ni;
        }
        if (rok) out4[obase + (long long)t * FF] =
            make_float4(sr[0], sr[1], sr[2], sr[3]);
        if (iok) out4[obase + imag_off4 + (long long)t * FF] =
            make_float4(si[0], si[1], si[2], si[3]);
    }
}

// ---- fallback: single-pass, thread = (b, f), if ws too small ----
__global__ __launch_bounds__(256) void
fb_kernel(const float* __restrict__ x,
          const float* __restrict__ mem_r,
          const float* __restrict__ mem_i,
          const float* __restrict__ a_vec,
          const float* __restrict__ b_vec,
          float* __restrict__ out,
          long long x_lim, long long mem_lim, long long out4_lim,
          long long imag_off4)
{
    const int g = blockIdx.x * 256 + threadIdx.x;   // [0, 8192)
    const int f = g & (FF - 1);
    const int b = g >> 10;

    float lr[CC], li[CC];
    make_lambda(a_vec, b_vec, f, lr, li);

    float sr[CC], si[CC];
#pragma unroll
    for (int c = 0; c < CC; ++c) {
        const long long m = (long long)(b * FF + f) * CC + c;
        sr[c] = (m < mem_lim) ? mem_r[m] : 0.f;
        si[c] = (m < mem_lim) ? mem_i[m] : 0.f;
    }

    const long long xbase = (long long)b * TT * FF + f;
    const bool xok = (xbase + (long long)(TT - 1) * FF) < x_lim;
    float4* out4 = (float4*)out;
    const bool rok = (xbase + (long long)(TT - 1) * FF) < out4_lim;
    const bool iok = (imag_off4 > 0) &&
                     ((xbase + imag_off4 + (long long)(TT - 1) * FF) < out4_lim);

    for (int t = 0; t < TT; ++t) {
        const float xv = xok ? x[xbase + (long long)t * FF] : 0.f;
#pragma unroll
        for (int c = 0; c < CC; ++c) {
            const float nr = fmaf(lr[c], sr[c], fmaf(-li[c], si[c], xv));
            const float ni = fmaf(li[c], sr[c], lr[c] * si[c]);
            sr[c] = nr; si[c] = ni;
        }
        if (rok) out4[xbase + (long long)t * FF] =
            make_float4(sr[0], sr[1], sr[2], sr[3]);
        if (iok) out4[xbase + imag_off4 + (long long)t * FF] =
            make_float4(si[0], si[1], si[2], si[3]);
    }
}

extern "C" void kernel_launch(void* const* d_in, const int* in_sizes, int n_in,
                              void* d_out, int out_size, void* d_ws, size_t ws_size,
                              hipStream_t stream)
{
    const float* x     = (const float*)d_in[0];
    const float* mem_r = (const float*)d_in[1];
    const float* mem_i = (const float*)d_in[2];
    const float* a_vec = (const float*)d_in[3];
    const float* b_vec = (const float*)d_in[4];
    float* out = (float*)d_out;

    const long long x_lim   = (long long)in_sizes[0];       // 4,194,304
    const long long mem_lim = (long long)in_sizes[1];       // 32,768
    const long long BTFC = (long long)BB * TT * FF * CC;    // 16,777,216
    const long long out4_lim = (long long)out_size / 4;
    // real-only (out_size == BTFC) vs planar real+imag (out_size == 2*BTFC)
    const long long imag_off4 = ((long long)out_size >= 2 * BTFC) ? (BTFC / 4) : 0;

    const long long buf_floats = (long long)NCH * BB * FF * 8;  // 1,048,576
    if (ws_size >= (size_t)(2 * buf_floats) * sizeof(float)) {
        float* ws_e = (float*)d_ws;
        float* ws_s = ws_e + buf_floats;
        p1_kernel<<<(BB * FF * NCH) / 256, 256, 0, stream>>>(
            x, a_vec, b_vec, ws_e, x_lim, buf_floats);
        comb_kernel<<<(BB * FF * CC) / 256, 256, 0, stream>>>(
            mem_r, mem_i, a_vec, b_vec, ws_e, ws_s, mem_lim, buf_floats);
        p2_kernel<<<(BB * FF * NCH) / 256, 256, 0, stream>>>(
            x, a_vec, b_vec, ws_s, out, x_lim, buf_floats, out4_lim, imag_off4);
    } else {
        fb_kernel<<<(BB * FF) / 256, 256, 0, stream>>>(
            x, mem_r, mem_i, a_vec, b_vec, out,
            x_lim, mem_lim, out4_lim, imag_off4);
    }
}

// Round 5
// 104.700 us; speedup vs baseline: 1.0312x; 1.0312x over previous
//
#include <hip/hip_runtime.h>
#include <math.h>

// OuterLaplaceAggregation: complex first-order linear scan.
//   s_t = lambda * s_{t-1} + x_t,  s_{-1} = memory
//   lambda_{f,c} = exp(clip(a[f],-LIMIT,-1e-8) + i*b[c])
// B=8 T=512 F=1024 C=4. Output written as real plane [b,t,f,c] and, if
// out_size >= 2*BTFC, a planar imag plane after it (both float4/thread).
//
// 2-kernel chunked scan, T = 32 chunks x 16:
//   p1: chunk-local end states (zero init)          -> ws_e
//   p2: per-thread lookback over ws_e + re-scan, nontemporal out stores
// 262144 threads/kernel = 16 waves/CU for latency hiding.

#define BB 8
#define TT 512
#define FF 1024
#define CC 4
#define NCH 32
#define LL (TT / NCH)          // 16
#define LIMIT_F 0.07664339751178941f

typedef float v4f __attribute__((ext_vector_type(4)));

__device__ __forceinline__ void make_lambda(const float* __restrict__ a_vec,
                                            const float* __restrict__ b_vec,
                                            int f, float lr[CC], float li[CC])
{
    const float af = fminf(fmaxf(a_vec[f], -LIMIT_F), -1e-8f);
    const float ea = expf(af);
#pragma unroll
    for (int c = 0; c < CC; ++c) {
        float s, cz;
        sincosf(b_vec[c], &s, &cz);
        lr[c] = ea * cz;
        li[c] = ea * s;
    }
}

// ws_e float index for chunk j, batch b, feature f (8 floats: 4x re,im)
#define WSE(j, b, f) ((((long long)(j) * BB + (b)) * FF + (f)) * 8)

// ---- p1: chunk-local scans, zero init. thread = (b, f, j) ----
__global__ __launch_bounds__(256) void
p1_kernel(const float* __restrict__ x,
          const float* __restrict__ a_vec,
          const float* __restrict__ b_vec,
          float* __restrict__ ws_e,
          long long x_lim, long long ws_lim)
{
    const int g = blockIdx.x * 256 + threadIdx.x;   // [0, 262144)
    const int f = g & (FF - 1);
    const int b = (g >> 10) & (BB - 1);
    const int j = g >> 13;                          // 0..31

    float lr[CC], li[CC];
    make_lambda(a_vec, b_vec, f, lr, li);

    const long long xbase = ((long long)b * TT + j * LL) * FF + f;
    const bool xok = (xbase + (long long)(LL - 1) * FF) < x_lim;

    float sr[CC] = {0.f, 0.f, 0.f, 0.f}, si[CC] = {0.f, 0.f, 0.f, 0.f};
#pragma unroll
    for (int t = 0; t < LL; ++t) {
        const float xv = xok ? x[xbase + (long long)t * FF] : 0.f;
#pragma unroll
        for (int c = 0; c < CC; ++c) {
            const float nr = fmaf(lr[c], sr[c], fmaf(-li[c], si[c], xv));
            const float ni = fmaf(li[c], sr[c], lr[c] * si[c]);
            sr[c] = nr; si[c] = ni;
        }
    }
    const long long w = WSE(j, b, f);
    if (w + 7 < ws_lim) {
        v4f* w4 = (v4f*)(ws_e + w);
        w4[0] = (v4f){sr[0], si[0], sr[1], si[1]};
        w4[1] = (v4f){sr[2], si[2], sr[3], si[3]};
    }
}

// ---- p2: per-thread lookback + re-scan + store. thread = (b, f, j) ----
__global__ __launch_bounds__(256) void
p2_kernel(const float* __restrict__ x,
          const float* __restrict__ mem_r,
          const float* __restrict__ mem_i,
          const float* __restrict__ a_vec,
          const float* __restrict__ b_vec,
          const float* __restrict__ ws_e,
          float* __restrict__ out,
          long long x_lim, long long mem_lim, long long ws_lim,
          long long out4_lim, long long imag_off4)
{
    const int g = blockIdx.x * 256 + threadIdx.x;   // [0, 262144)
    const int f = g & (FF - 1);
    const int b = (g >> 10) & (BB - 1);
    const int j = g >> 13;                          // wave-uniform

    float lr[CC], li[CC];
    make_lambda(a_vec, b_vec, f, lr, li);

    // lambda^LL per c
    const float af = fminf(fmaxf(a_vec[f], -LIMIT_F), -1e-8f);
    const float eaL = expf(af * (float)LL);
    float lLr[CC], lLi[CC];
#pragma unroll
    for (int c = 0; c < CC; ++c) {
        float s, cz;
        sincosf(b_vec[c] * (float)LL, &s, &cz);
        lLr[c] = eaL * cz;
        lLi[c] = eaL * s;
    }

    // seed = memory
    float sr[CC], si[CC];
#pragma unroll
    for (int c = 0; c < CC; ++c) {
        const long long m = (long long)(b * FF + f) * CC + c;
        sr[c] = (m < mem_lim) ? mem_r[m] : 0.f;
        si[c] = (m < mem_lim) ? mem_i[m] : 0.f;
    }

    // lookback: fold chunk end-states 0..j-1 (j wave-uniform; ws_e in L2)
    for (int i = 0; i < j; ++i) {
        const long long w = WSE(i, b, f);
        v4f A = (v4f){0.f, 0.f, 0.f, 0.f}, Bv = A;
        if (w + 7 < ws_lim) {
            const v4f* w4 = (const v4f*)(ws_e + w);
            A = w4[0]; Bv = w4[1];
        }
        const float er[CC] = {A.x, A.z, Bv.x, Bv.z};
        const float ei[CC] = {A.y, A.w, Bv.y, Bv.w};
#pragma unroll
        for (int c = 0; c < CC; ++c) {
            const float nr = fmaf(lLr[c], sr[c], fmaf(-lLi[c], si[c], er[c]));
            const float ni = fmaf(lLi[c], sr[c], fmaf(lLr[c], si[c], ei[c]));
            sr[c] = nr; si[c] = ni;
        }
    }

    // re-scan chunk, write out (real plane + optional planar imag)
    const long long xbase = ((long long)b * TT + j * LL) * FF + f;
    const bool xok = (xbase + (long long)(LL - 1) * FF) < x_lim;
    v4f* out4 = (v4f*)out;
    const long long obase = xbase;   // float4 index: (b*T + t)*F + f
    const bool rok = (obase + (long long)(LL - 1) * FF) < out4_lim;
    const bool iok = (imag_off4 > 0) &&
                     ((obase + imag_off4 + (long long)(LL - 1) * FF) < out4_lim);

#pragma unroll
    for (int t = 0; t < LL; ++t) {
        const float xv = xok ? x[xbase + (long long)t * FF] : 0.f;
#pragma unroll
        for (int c = 0; c < CC; ++c) {
            const float nr = fmaf(lr[c], sr[c], fmaf(-li[c], si[c], xv));
            const float ni = fmaf(li[c], sr[c], lr[c] * si[c]);
            sr[c] = nr; si[c] = ni;
        }
        if (rok) __builtin_nontemporal_store(
            (v4f){sr[0], sr[1], sr[2], sr[3]},
            &out4[obase + (long long)t * FF]);
        if (iok) __builtin_nontemporal_store(
            (v4f){si[0], si[1], si[2], si[3]},
            &out4[obase + imag_off4 + (long long)t * FF]);
    }
}

// ---- fallback: single-pass, thread = (b, f), if ws too small ----
__global__ __launch_bounds__(256) void
fb_kernel(const float* __restrict__ x,
          const float* __restrict__ mem_r,
          const float* __restrict__ mem_i,
          const float* __restrict__ a_vec,
          const float* __restrict__ b_vec,
          float* __restrict__ out,
          long long x_lim, long long mem_lim, long long out4_lim,
          long long imag_off4)
{
    const int g = blockIdx.x * 256 + threadIdx.x;   // [0, 8192)
    const int f = g & (FF - 1);
    const int b = g >> 10;

    float lr[CC], li[CC];
    make_lambda(a_vec, b_vec, f, lr, li);

    float sr[CC], si[CC];
#pragma unroll
    for (int c = 0; c < CC; ++c) {
        const long long m = (long long)(b * FF + f) * CC + c;
        sr[c] = (m < mem_lim) ? mem_r[m] : 0.f;
        si[c] = (m < mem_lim) ? mem_i[m] : 0.f;
    }

    const long long xbase = (long long)b * TT * FF + f;
    const bool xok = (xbase + (long long)(TT - 1) * FF) < x_lim;
    v4f* out4 = (v4f*)out;
    const bool rok = (xbase + (long long)(TT - 1) * FF) < out4_lim;
    const bool iok = (imag_off4 > 0) &&
                     ((xbase + imag_off4 + (long long)(TT - 1) * FF) < out4_lim);

    for (int t = 0; t < TT; ++t) {
        const float xv = xok ? x[xbase + (long long)t * FF] : 0.f;
#pragma unroll
        for (int c = 0; c < CC; ++c) {
            const float nr = fmaf(lr[c], sr[c], fmaf(-li[c], si[c], xv));
            const float ni = fmaf(li[c], sr[c], lr[c] * si[c]);
            sr[c] = nr; si[c] = ni;
        }
        if (rok) out4[xbase + (long long)t * FF] =
            (v4f){sr[0], sr[1], sr[2], sr[3]};
        if (iok) out4[xbase + imag_off4 + (long long)t * FF] =
            (v4f){si[0], si[1], si[2], si[3]};
    }
}

extern "C" void kernel_launch(void* const* d_in, const int* in_sizes, int n_in,
                              void* d_out, int out_size, void* d_ws, size_t ws_size,
                              hipStream_t stream)
{
    const float* x     = (const float*)d_in[0];
    const float* mem_r = (const float*)d_in[1];
    const float* mem_i = (const float*)d_in[2];
    const float* a_vec = (const float*)d_in[3];
    const float* b_vec = (const float*)d_in[4];
    float* out = (float*)d_out;

    const long long x_lim   = (long long)in_sizes[0];       // 4,194,304
    const long long mem_lim = (long long)in_sizes[1];       // 32,768
    const long long BTFC = (long long)BB * TT * FF * CC;    // 16,777,216
    const long long out4_lim = (long long)out_size / 4;
    const long long imag_off4 = ((long long)out_size >= 2 * BTFC) ? (BTFC / 4) : 0;

    const long long ws_floats = (long long)NCH * BB * FF * 8;   // 2,097,152
    if (ws_size >= (size_t)ws_floats * sizeof(float)) {
        float* ws_e = (float*)d_ws;
        const int threads = BB * FF * NCH;                  // 262144
        p1_kernel<<<threads / 256, 256, 0, stream>>>(
            x, a_vec, b_vec, ws_e, x_lim, ws_floats);
        p2_kernel<<<threads / 256, 256, 0, stream>>>(
            x, mem_r, mem_i, a_vec, b_vec, ws_e, out,
            x_lim, mem_lim, ws_floats, out4_lim, imag_off4);
    } else {
        fb_kernel<<<(BB * FF) / 256, 256, 0, stream>>>(
            x, mem_r, mem_i, a_vec, b_vec, out,
            x_lim, mem_lim, out4_lim, imag_off4);
    }
}